// Round 6
// baseline (401.896 us; speedup 1.0000x reference)
//
#include <hip/hip_runtime.h>
#include <hip/hip_bf16.h>

#define BSZ 4
#define SEQ 2048
#define DMODEL 1024
#define DINNER 2048
#define DSTATE 64
#define NH 32
#define HD 64
#define CKL 64            // chunk length
#define NCH 32            // chunks per sequence
#define CONVD 2176
#define DPROJ 4256
#define N1 4224           // GEMM1 N = DINNER + CONVD = 33*128 (dt cols handled separately)
#define MTOT 8192         // BSZ*SEQ
#define YSTR 72           // LDS row stride (bf16): 144 B, keeps 16B alignment

typedef __hip_bfloat16 bf16;
typedef __attribute__((ext_vector_type(8))) short short8;   // 8 bf16 (4 VGPRs)
typedef __attribute__((ext_vector_type(4))) short short4_;  // 8 bytes
typedef __attribute__((ext_vector_type(4))) float f32x4;

__device__ __forceinline__ float sigmoidf_(float x) { return 1.0f / (1.0f + __expf(-x)); }
__device__ __forceinline__ float bits2f(short s) { return __uint_as_float(((unsigned)(unsigned short)s) << 16); }
__device__ __forceinline__ short f2bits(float f) {
    bf16 h = __float2bfloat16(f);
    return *reinterpret_cast<short*>(&h);
}

__device__ __forceinline__ void gl_lds16(const bf16* g, bf16* l) {
    __builtin_amdgcn_global_load_lds((const __attribute__((address_space(1))) void*)g,
                                     (__attribute__((address_space(3))) void*)l, 16, 0, 0);
}

__device__ __forceinline__ void store_val(float* p, float v) { *p = v; }
__device__ __forceinline__ void store_val(bf16* p, float v) { *p = __float2bfloat16(v); }

// ---------------- fp32 -> bf16 convert (vectorized: 4 elems/thread; n % 4 == 0) ----------------
__global__ void k_cvt(const float* __restrict__ src, bf16* __restrict__ dst, int n) {
    int i = blockIdx.x * 256 + threadIdx.x;
    int g = i * 4;
    if (g < n) {
        f32x4 f = *(const f32x4*)&src[g];
        short4_ o;
#pragma unroll
        for (int j = 0; j < 4; j++) o[j] = f2bits(f[j]);
        *(short4_*)&dst[g] = o;
    }
}

// ---------------- bf16 MFMA GEMM: C[M][N] = A[M][K] * W[N][K]^T ----------------
// 128x128 tile, BK=64, XOR-swizzled LDS columns (conflict-free, verified R5: SQ_LDS_BANK_CONFLICT=0).
template <typename TOUT>
__global__ __launch_bounds__(256) void k_gemm_bt(const bf16* __restrict__ A, const bf16* __restrict__ W,
                                                 TOUT* __restrict__ C, int N, int K) {
    __shared__ __align__(16) bf16 lA[128 * 64];
    __shared__ __align__(16) bf16 lB[128 * 64];
    const int tid = threadIdx.x;
    const int lane = tid & 63, w = tid >> 6;
    const int wm = w >> 1, wn = w & 1;
    const int lr = lane & 15, lk = lane >> 4;
    const int m0 = blockIdx.y * 128, n0 = blockIdx.x * 128;

    f32x4 acc[4][4];
#pragma unroll
    for (int i = 0; i < 4; i++)
#pragma unroll
        for (int j = 0; j < 4; j++) acc[i][j] = (f32x4){0.f, 0.f, 0.f, 0.f};

    const int r = tid >> 3;
    const int cs = ((tid & 7) ^ (r & 7)) * 8;
    const bf16* ga = A + (size_t)(m0 + r) * K + cs;
    const bf16* gb = W + (size_t)(n0 + r) * K + cs;
    bf16* la0 = lA + tid * 8;
    bf16* lb0 = lB + tid * 8;
    const int sx = (lr & 7);

    for (int kt = 0; kt < K; kt += 64) {
#pragma unroll
        for (int i = 0; i < 4; i++) {
            gl_lds16(ga + kt + (size_t)(32 * i) * K, la0 + 2048 * i);
            gl_lds16(gb + kt + (size_t)(32 * i) * K, lb0 + 2048 * i);
        }
        __syncthreads();
#pragma unroll
        for (int hh = 0; hh < 2; hh++) {
            const int cb = ((lk + 4 * hh) ^ sx) * 8;
            short8 af[4], bfr[4];
#pragma unroll
            for (int im = 0; im < 4; im++)
                af[im] = *(const short8*)&lA[(wm * 64 + im * 16 + lr) * 64 + cb];
#pragma unroll
            for (int jn = 0; jn < 4; jn++)
                bfr[jn] = *(const short8*)&lB[(wn * 64 + jn * 16 + lr) * 64 + cb];
#pragma unroll
            for (int im = 0; im < 4; im++)
#pragma unroll
                for (int jn = 0; jn < 4; jn++)
                    acc[im][jn] = __builtin_amdgcn_mfma_f32_16x16x32_bf16(af[im], bfr[jn], acc[im][jn], 0, 0, 0);
        }
        __syncthreads();
    }
#pragma unroll
    for (int im = 0; im < 4; im++) {
        int row = m0 + wm * 64 + im * 16 + lk * 4;
#pragma unroll
        for (int jn = 0; jn < 4; jn++) {
            int col = n0 + wn * 64 + jn * 16 + lr;
            TOUT* cp = C + (size_t)row * N + col;
#pragma unroll
            for (int rr = 0; rr < 4; rr++) store_val(cp + (size_t)rr * N, acc[im][jn][rr]);
        }
    }
}

// ---------------- fused: u row -> bf16 + dt projection (dt stored TRANSPOSED [h][t]) ----------------
__global__ __launch_bounds__(256) void k_prep(const float* __restrict__ u, const float* __restrict__ W_in,
                                              const float* __restrict__ dt_bias,
                                              bf16* __restrict__ u_b, float* __restrict__ dtt) {
    __shared__ __align__(16) float us[8 * DMODEL];
    const int t0 = blockIdx.x * 8;
    const int tid = threadIdx.x;
    const float* ur = u + (size_t)t0 * DMODEL;
    bf16* ub = u_b + (size_t)t0 * DMODEL;
#pragma unroll
    for (int i = 0; i < 8; i++) {
        int idx = (i * 256 + tid) * 4;
        f32x4 v = *(const f32x4*)&ur[idx];
        *(f32x4*)&us[idx] = v;
        short4_ o;
#pragma unroll
        for (int j = 0; j < 4; j++) o[j] = f2bits(v[j]);
        *(short4_*)&ub[idx] = o;
    }
    __syncthreads();
    const int h = tid >> 3, sub = tid & 7;
    const float* wr = W_in + (size_t)(DPROJ - NH + h) * DMODEL;
    float s[8] = {};
    for (int k = sub * 4; k < DMODEL; k += 32) {
        f32x4 w4 = *(const f32x4*)&wr[k];
#pragma unroll
        for (int rr = 0; rr < 8; rr++) {
            const float* up = &us[rr * DMODEL + k];
            s[rr] += up[0] * w4[0] + up[1] * w4[1] + up[2] * w4[2] + up[3] * w4[3];
        }
    }
#pragma unroll
    for (int rr = 0; rr < 8; rr++) {
        s[rr] += __shfl_down(s[rr], 4, 8);
        s[rr] += __shfl_down(s[rr], 2, 8);
        s[rr] += __shfl_down(s[rr], 1, 8);
    }
    if (sub == 0) {
        float bh = dt_bias[h];
#pragma unroll
        for (int rr = 0; rr < 8; rr++) {
            float x = s[rr] + bh;
            dtt[(size_t)h * MTOT + t0 + rr] = (x > 20.f) ? x : log1pf(__expf(x));
        }
    }
}

// ---------------- depthwise causal conv (width 4) + bias + SiLU — 4 channels/thread ----------------
__global__ void k_conv(const bf16* __restrict__ zx, const float* __restrict__ cw,
                       const float* __restrict__ cb, bf16* __restrict__ xbc) {
    int i = blockIdx.x * 256 + threadIdx.x;
    int g = i * 4;
    if (g >= MTOT * CONVD) return;
    int c0 = g % CONVD;
    int t = g / CONVD;
    int s = t & (SEQ - 1);
    const short* base = (const short*)(zx + (size_t)t * N1 + DINNER + c0);
    f32x4 w0 = *(const f32x4*)&cw[(c0 + 0) * 4];
    f32x4 w1 = *(const f32x4*)&cw[(c0 + 1) * 4];
    f32x4 w2 = *(const f32x4*)&cw[(c0 + 2) * 4];
    f32x4 w3 = *(const f32x4*)&cw[(c0 + 3) * 4];
    f32x4 a = *(const f32x4*)&cb[c0];
#pragma unroll
    for (int k = 0; k < 4; k++) {
        int st = s - 3 + k;
        if (st >= 0) {
            short4_ v = *(const short4_*)(base + (long)(k - 3) * N1);
            a[0] += bits2f(v[0]) * w0[k];
            a[1] += bits2f(v[1]) * w1[k];
            a[2] += bits2f(v[2]) * w2[k];
            a[3] += bits2f(v[3]) * w3[k];
        }
    }
    short4_ o;
#pragma unroll
    for (int j = 0; j < 4; j++) o[j] = f2bits(a[j] * sigmoidf_(a[j]));
    *(short4_*)&xbc[g] = o;
}

// ---------------- fused SSD scan: per (p-half, h, b) block walks all 32 chunks sequentially ----------
// Running state S[32][64] in fp32 LDS. Per chunk, 4 MFMA matmuls:
//   P1 Y_off = C·S0^T (scaled exp(Ac[l])); P2 G = C·B^T masked/decayed; P3 Y += G·X;
//   P4 Snew = Xd·Bn^T (decay sf[l] folded into Xd); S = S*exp(tot) + Snew.
// Register prefetch of chunk c+1 issued at compute start (2 barriers/chunk keeps loads in flight).
// dt-scan for chunk c+1 computed by wave0 during chunk c (double-buffered by parity).
__global__ __launch_bounds__(256) void k_ssd(const bf16* __restrict__ xbc, const float* __restrict__ dtt,
                                             const float* __restrict__ A_log, const float* __restrict__ Dp,
                                             bf16* __restrict__ zx) {
    __shared__ __align__(16) short Ct[64 * YSTR];    // C [l][n]; reused as Y [l][p] in epilogue
    __shared__ __align__(16) short Bt[64 * YSTR];    // B [s][n]
    __shared__ __align__(16) short Bn[64 * YSTR];    // B^T [n][l]
    __shared__ __align__(16) short Xt[32 * YSTR];    // X^T [p][l]
    __shared__ __align__(16) short Xd[32 * YSTR];    // X^T * sf[l]
    __shared__ __align__(16) short Sb[32 * YSTR];    // S0 bf16 [p][n]
    __shared__ __align__(16) short Gs[4 * 16 * YSTR];// per-wave G
    __shared__ __align__(16) float Sf[32 * 68];      // running state fp32 [p][n]
    __shared__ float sdt2[2][64], sAc2[2][64], sf2[2][64], set2[2];

    const int ph = blockIdx.x, h = blockIdx.y, b = blockIdx.z;
    const int tid = threadIdx.x;
    const int lane = tid & 63, w = tid >> 6;
    const int lr = lane & 15, lk = lane >> 4;
    const float Ah = -__expf(A_log[h]);
    const float Dh = Dp[h];
    const int xcol = h * HD + ph * 32;

    const int lrow = tid >> 2, c0 = (tid & 3) * 16, px = (tid & 3) * 8;
    const int zl = 16 * w + (lane >> 2), zp = (lane & 3) * 8;

    short8 rC0, rC1, rB0, rB1, rX, rZ;
    float rdt;
    auto load_chunk = [&](int cc) {
        int rows0 = b * SEQ + cc * CKL;
        const short* rp = (const short*)(xbc + (size_t)(rows0 + lrow) * CONVD);
        rC0 = *(const short8*)&rp[DINNER + DSTATE + c0];
        rC1 = *(const short8*)&rp[DINNER + DSTATE + c0 + 8];
        rB0 = *(const short8*)&rp[DINNER + c0];
        rB1 = *(const short8*)&rp[DINNER + c0 + 8];
        rX  = *(const short8*)&rp[xcol + px];
        rZ  = *(const short8*)((const short*)zx + (size_t)(rows0 + zl) * N1 + xcol + zp);
        rdt = dtt[(size_t)h * MTOT + rows0 + lane];
    };

    for (int i = tid; i < 32 * 68; i += 256) Sf[i] = 0.f;
    load_chunk(0);
    if (tid < 64) {
        float dv = rdt;
        float v = Ah * dv;
#pragma unroll
        for (int d = 1; d < 64; d <<= 1) { float o = __shfl_up(v, d); if (tid >= d) v += o; }
        float tot = __shfl(v, 63);
        sdt2[0][tid] = dv; sAc2[0][tid] = v; sf2[0][tid] = __expf(tot - v) * dv;
        if (tid == 63) set2[0] = __expf(tot);
    }
    __syncthreads();

    for (int c = 0; c < NCH; c++) {
        const int par = c & 1;
        const int rows0 = b * SEQ + c * CKL;
        // ---- phase A: scatter regs -> LDS; build Sb from Sf ----
        *(short8*)&Ct[lrow * YSTR + c0] = rC0;
        *(short8*)&Ct[lrow * YSTR + c0 + 8] = rC1;
        *(short8*)&Bt[lrow * YSTR + c0] = rB0;
        *(short8*)&Bt[lrow * YSTR + c0 + 8] = rB1;
#pragma unroll
        for (int j = 0; j < 8; j++) {
            Bn[(c0 + j) * YSTR + lrow] = rB0[j];
            Bn[(c0 + 8 + j) * YSTR + lrow] = rB1[j];
        }
        float sfl = sf2[par][lrow];
#pragma unroll
        for (int j = 0; j < 8; j++) {
            Xt[(px + j) * YSTR + lrow] = rX[j];
            Xd[(px + j) * YSTR + lrow] = f2bits(bits2f(rX[j]) * sfl);
        }
        {
            int sp = tid >> 3, sn = (tid & 7) * 8;
            f32x4 a0 = *(const f32x4*)&Sf[sp * 68 + sn];
            f32x4 a1 = *(const f32x4*)&Sf[sp * 68 + sn + 4];
            short8 o;
#pragma unroll
            for (int j = 0; j < 4; j++) { o[j] = f2bits(a0[j]); o[4 + j] = f2bits(a1[j]); }
            *(short8*)&Sb[sp * YSTR + sn] = o;
        }
        __syncthreads();

        // ---- phase E: prefetch c+1, then compute ----
        float etot = set2[par];
        short8 zcur = rZ;
        if (c + 1 < NCH) load_chunk(c + 1);

        short8 cf0 = *(const short8*)&Ct[(16 * w + lr) * YSTR + lk * 8];
        short8 cf1 = *(const short8*)&Ct[(16 * w + lr) * YSTR + 32 + lk * 8];
        // P1: Y_off = C * S0^T
        f32x4 acc[2];
#pragma unroll
        for (int t = 0; t < 2; t++) {
            short8 s0 = *(const short8*)&Sb[(16 * t + lr) * YSTR + lk * 8];
            short8 s1 = *(const short8*)&Sb[(16 * t + lr) * YSTR + 32 + lk * 8];
            acc[t] = __builtin_amdgcn_mfma_f32_16x16x32_bf16(cf0, s0, (f32x4){0.f, 0.f, 0.f, 0.f}, 0, 0, 0);
            acc[t] = __builtin_amdgcn_mfma_f32_16x16x32_bf16(cf1, s1, acc[t], 0, 0, 0);
        }
        float sAcl[4], el[4];
#pragma unroll
        for (int rr = 0; rr < 4; rr++) { sAcl[rr] = sAc2[par][16 * w + lk * 4 + rr]; el[rr] = __expf(sAcl[rr]); }
#pragma unroll
        for (int t = 0; t < 2; t++)
#pragma unroll
            for (int rr = 0; rr < 4; rr++) acc[t][rr] *= el[rr];
        // P2: G = C * B^T, mask/decay, wave-private LDS round-trip
        short* gw = Gs + w * 16 * YSTR;
#pragma unroll
        for (int t = 0; t < 4; t++) {
            short8 b0 = *(const short8*)&Bt[(16 * t + lr) * YSTR + lk * 8];
            short8 b1 = *(const short8*)&Bt[(16 * t + lr) * YSTR + 32 + lk * 8];
            f32x4 g = __builtin_amdgcn_mfma_f32_16x16x32_bf16(cf0, b0, (f32x4){0.f, 0.f, 0.f, 0.f}, 0, 0, 0);
            g = __builtin_amdgcn_mfma_f32_16x16x32_bf16(cf1, b1, g, 0, 0, 0);
            int s = 16 * t + lr;
            float sAcs = sAc2[par][s], dts = sdt2[par][s];
#pragma unroll
            for (int rr = 0; rr < 4; rr++) {
                int l = 16 * w + lk * 4 + rr;
                float v = (s <= l) ? g[rr] * __expf(sAcl[rr] - sAcs) * dts : 0.f;
                gw[(lk * 4 + rr) * YSTR + s] = f2bits(v);
            }
        }
        // P3: Y += G * X
        short8 gf0 = *(const short8*)&gw[lr * YSTR + lk * 8];
        short8 gf1 = *(const short8*)&gw[lr * YSTR + 32 + lk * 8];
#pragma unroll
        for (int t = 0; t < 2; t++) {
            short8 x0 = *(const short8*)&Xt[(16 * t + lr) * YSTR + lk * 8];
            short8 x1 = *(const short8*)&Xt[(16 * t + lr) * YSTR + 32 + lk * 8];
            acc[t] = __builtin_amdgcn_mfma_f32_16x16x32_bf16(gf0, x0, acc[t], 0, 0, 0);
            acc[t] = __builtin_amdgcn_mfma_f32_16x16x32_bf16(gf1, x1, acc[t], 0, 0, 0);
        }
        // P4: Snew = Xd * Bn^T ; Sf = Sf*etot + Snew  (disjoint 16x32 region per wave)
        {
            int pw = w & 1, nh2 = w >> 1;
            short8 xd0 = *(const short8*)&Xd[(16 * pw + lr) * YSTR + lk * 8];
            short8 xd1 = *(const short8*)&Xd[(16 * pw + lr) * YSTR + 32 + lk * 8];
#pragma unroll
            for (int j = 0; j < 2; j++) {
                int nt = 2 * nh2 + j;
                short8 b0 = *(const short8*)&Bn[(16 * nt + lr) * YSTR + lk * 8];
                short8 b1 = *(const short8*)&Bn[(16 * nt + lr) * YSTR + 32 + lk * 8];
                f32x4 sacc = __builtin_amdgcn_mfma_f32_16x16x32_bf16(xd0, b0, (f32x4){0.f, 0.f, 0.f, 0.f}, 0, 0, 0);
                sacc = __builtin_amdgcn_mfma_f32_16x16x32_bf16(xd1, b1, sacc, 0, 0, 0);
#pragma unroll
                for (int rr = 0; rr < 4; rr++) {
                    int n = 16 * nt + lr;
                    int p = 16 * pw + lk * 4 + rr;
                    Sf[p * 68 + n] = Sf[p * 68 + n] * etot + sacc[rr];
                }
            }
        }
        // Y epilogue (+D*x) into Ct's own wave rows; then coalesced z-gate with prefetched z
#pragma unroll
        for (int t = 0; t < 2; t++) {
#pragma unroll
            for (int rr = 0; rr < 4; rr++) {
                int p = 16 * t + lr;
                int l = 16 * w + lk * 4 + rr;
                float y = acc[t][rr] + Dh * bits2f(Xt[p * YSTR + l]);
                Ct[l * YSTR + p] = f2bits(y);
            }
        }
        {
            short8 y8 = *(const short8*)&Ct[zl * YSTR + zp];
            short* zpp = (short*)zx + (size_t)(rows0 + zl) * N1 + xcol + zp;
            short8 o;
#pragma unroll
            for (int j = 0; j < 8; j++) {
                float z = bits2f(zcur[j]);
                o[j] = f2bits(bits2f(y8[j]) * (z * sigmoidf_(z)));
            }
            *(short8*)zpp = o;
        }
        // wave0: dt-scan for chunk c+1 (other parity buffers)
        if (c + 1 < NCH && tid < 64) {
            int p2 = (c + 1) & 1;
            float dv = rdt;
            float v = Ah * dv;
#pragma unroll
            for (int d = 1; d < 64; d <<= 1) { float o = __shfl_up(v, d); if (tid >= d) v += o; }
            float tot = __shfl(v, 63);
            sdt2[p2][tid] = dv; sAc2[p2][tid] = v; sf2[p2][tid] = __expf(tot - v) * dv;
            if (tid == 63) set2[p2] = __expf(tot);
        }
        __syncthreads();
    }
}

// ---------------- RMSNorm over DINNER + bf16 cast for GEMM2 (contiguous 16B/lane) ----------------
__global__ __launch_bounds__(256) void k_norm(const bf16* __restrict__ zx, const float* __restrict__ nw,
                                              bf16* __restrict__ yb) {
    __shared__ float red[4];
    int t = blockIdx.x, tid = threadIdx.x;
    const short* row = (const short*)(zx + (size_t)t * N1);
    short8 v8 = *(const short8*)&row[tid * 8];
    float v[8];
    float ss = 0.f;
#pragma unroll
    for (int i = 0; i < 8; i++) {
        v[i] = bits2f(v8[i]);
        ss += v[i] * v[i];
    }
#pragma unroll
    for (int d = 32; d > 0; d >>= 1) ss += __shfl_down(ss, d);
    if ((tid & 63) == 0) red[tid >> 6] = ss;
    __syncthreads();
    float scale = rsqrtf((red[0] + red[1] + red[2] + red[3]) * (1.0f / DINNER) + 1e-5f);
    f32x4 w0 = *(const f32x4*)&nw[tid * 8];
    f32x4 w1 = *(const f32x4*)&nw[tid * 8 + 4];
    short8 o;
#pragma unroll
    for (int i = 0; i < 4; i++) o[i] = f2bits(v[i] * scale * w0[i]);
#pragma unroll
    for (int i = 0; i < 4; i++) o[4 + i] = f2bits(v[4 + i] * scale * w1[i]);
    *(short8*)&((short*)yb)[(size_t)t * DINNER + tid * 8] = o;
}

extern "C" void kernel_launch(void* const* d_in, const int* in_sizes, int n_in,
                              void* d_out, int out_size, void* d_ws, size_t ws_size,
                              hipStream_t stream) {
    const float* u       = (const float*)d_in[0];
    const float* W_in    = (const float*)d_in[1];
    const float* conv_w  = (const float*)d_in[2];
    const float* conv_b  = (const float*)d_in[3];
    const float* dt_bias = (const float*)d_in[4];
    const float* A_log   = (const float*)d_in[5];
    const float* Dp      = (const float*)d_in[6];
    const float* norm_w  = (const float*)d_in[7];
    const float* W_out   = (const float*)d_in[8];
    float* out = (float*)d_out;

    // Workspace layout (~108 MiB total):
    char* ws = (char*)d_ws;
    bf16* zx     = (bf16*)ws;  ws += (size_t)MTOT * N1 * 2;       // 69.2 MB
    bf16* xbc    = (bf16*)ws;  ws += (size_t)MTOT * CONVD * 2;    // 34 MB (reused as y_b)
    bf16* wout_b = (bf16*)ws;  ws += (size_t)DMODEL * DINNER * 2; // 4 MB
    float* dtt   = (float*)ws; ws += (size_t)NH * MTOT * 4;       // 1 MB, [h][t]
    bf16* y_b    = (bf16*)xbc;  // xbc dead after k_ssd; y_b written by k_norm after

    // d_out (32 MiB) doubles as scratch for GEMM1 inputs only.
    bf16* u_b   = (bf16*)d_out;                                      // 16 MB
    bf16* win_b = (bf16*)((char*)d_out + (size_t)MTOT * DMODEL * 2); // 8.25 MB

    k_prep<<<MTOT / 8, 256, 0, stream>>>(u, W_in, dt_bias, u_b, dtt);
    k_cvt<<<(N1 * DMODEL / 4 + 255) / 256, 256, 0, stream>>>(W_in, win_b, N1 * DMODEL);
    k_cvt<<<(DMODEL * DINNER / 4 + 255) / 256, 256, 0, stream>>>(W_out, wout_b, DMODEL * DINNER);

    k_gemm_bt<bf16><<<dim3(N1 / 128, MTOT / 128), 256, 0, stream>>>(u_b, win_b, zx, N1, DMODEL);

    k_conv<<<(MTOT * CONVD / 4 + 255) / 256, 256, 0, stream>>>(zx, conv_w, conv_b, xbc);

    k_ssd<<<dim3(2, NH, BSZ), 256, 0, stream>>>(xbc, dtt, A_log, Dp, zx);

    k_norm<<<MTOT, 256, 0, stream>>>(zx, norm_w, y_b);

    k_gemm_bt<float><<<dim3(DMODEL / 128, MTOT / 128), 256, 0, stream>>>(y_b, wout_b, out, DMODEL, DINNER);
}